// Round 4
// baseline (319.299 us; speedup 1.0000x reference)
//
#include <hip/hip_runtime.h>
#include <hip/hip_bf16.h>

#define NHID 128
#define NGRAPH 512
#define NCLS 10

typedef __attribute__((ext_vector_type(8))) short bf16x8;
typedef __attribute__((ext_vector_type(4))) float f32x4;
typedef __attribute__((ext_vector_type(4))) unsigned int u32x4;

// order-preserving float<->uint encoding for atomicMax-based segment max
__device__ inline unsigned int fenc(float f) {
    unsigned int u = __float_as_uint(f);
    return (u & 0x80000000u) ? ~u : (u | 0x80000000u);
}
__device__ inline float fdec(unsigned int u) {
    u = (u & 0x80000000u) ? (u & 0x7fffffffu) : ~u;
    return __uint_as_float(u);
}
// f32 -> bf16 round-to-nearest-even (finite inputs)
__device__ inline unsigned short f2bf(float f) {
    unsigned int u = __float_as_uint(f);
    return (unsigned short)((u + 0x7fffu + ((u >> 16) & 1u)) >> 16);
}
__device__ inline unsigned int packbf(float lo, float hi) {
    return (unsigned)f2bf(lo) | ((unsigned)f2bf(hi) << 16);
}

__global__ void k_deg(const int* __restrict__ dst, int* __restrict__ cnt, int E) {
    int e = blockIdx.x * blockDim.x + threadIdx.x;
    if (e < E) atomicAdd(&cnt[dst[e]], 1);
}

// phase 1: per-block (1024-wide) inclusive scan of cnt into rowptr[i+1],
// block totals into bsum, and dinv as a free rider.
__global__ __launch_bounds__(1024) void k_scan1(const int* __restrict__ cnt,
        float* __restrict__ dinv, int* __restrict__ rowptr,
        int* __restrict__ bsum, int N) {
    __shared__ int lds[1024];
    int t = threadIdx.x;
    int i = blockIdx.x * 1024 + t;
    int v = (i < N) ? cnt[i] : 0;
    if (i < N) dinv[i] = rsqrtf((float)v + 1.0f);
    lds[t] = v;
    __syncthreads();
    for (int off = 1; off < 1024; off <<= 1) {
        int x = (t >= off) ? lds[t - off] : 0;
        __syncthreads();
        lds[t] += x;
        __syncthreads();
    }
    if (i < N) rowptr[i + 1] = lds[t];
    if (t == 1023) bsum[blockIdx.x] = lds[1023];
}

// phase 2: exclusive scan of nb block sums (nb <= 1024), in place
__global__ __launch_bounds__(1024) void k_scan2(int* __restrict__ bsum, int nb) {
    __shared__ int lds[1024];
    int t = threadIdx.x;
    int v = (t < nb) ? bsum[t] : 0;
    lds[t] = v;
    __syncthreads();
    for (int off = 1; off < 1024; off <<= 1) {
        int x = (t >= off) ? lds[t - off] : 0;
        __syncthreads();
        lds[t] += x;
        __syncthreads();
    }
    if (t < nb) bsum[t] = lds[t] - v;
}

// phase 3: add block offsets; rowptr[0]=0
__global__ void k_scan3(int* __restrict__ rowptr, const int* __restrict__ bsum, int N) {
    int i = blockIdx.x * 256 + threadIdx.x;
    if (i < N) rowptr[i + 1] += bsum[i >> 10];
    if (i == 0) rowptr[0] = 0;
}

// build packed CSR entries: (src, norm) in one 8B element
__global__ void k_fill(const int* __restrict__ src, const int* __restrict__ dst,
                       const float* __restrict__ dinv, const int* __restrict__ rowptr,
                       int* __restrict__ cursor, int2* __restrict__ csr, int E) {
    int e = blockIdx.x * blockDim.x + threadIdx.x;
    if (e >= E) return;
    int s = src[e], d = dst[e];
    int pos = rowptr[d] + atomicAdd(&cursor[d], 1);
    csr[pos] = make_int2(s, __float_as_int(dinv[s] * dinv[d]));
}

// x f32 [N,128] -> bf16 (each thread converts 8 elements)
__global__ void k_xbf(const float* __restrict__ x, unsigned int* __restrict__ xb, int n8) {
    int i = blockIdx.x * 256 + threadIdx.x;
    if (i >= n8) return;
    const float* p = x + (size_t)i * 8;
    f32x4 a = *reinterpret_cast<const f32x4*>(p);
    f32x4 b = *reinterpret_cast<const f32x4*>(p + 4);
    u32x4 o;
    o[0] = packbf(a[0], a[1]);
    o[1] = packbf(a[2], a[3]);
    o[2] = packbf(b[0], b[1]);
    o[3] = packbf(b[2], b[3]);
    *reinterpret_cast<u32x4*>(xb + (size_t)i * 4) = o;
}

// transpose all three W [128x128] f32 -> Wt[l] [c][k] bf16
__global__ void k_wt3(const float* __restrict__ W1, const float* __restrict__ W2,
                      const float* __restrict__ W3, unsigned short* __restrict__ Wt) {
    int idx = blockIdx.x * 256 + threadIdx.x;   // 3*16384
    int l = idx >> 14;
    int r = idx & 16383;
    const float* W = (l == 0) ? W1 : (l == 1) ? W2 : W3;
    int c = r & 127, k = r >> 7;
    Wt[l * 16384 + c * NHID + k] = f2bf(W[k * NHID + c]);
}

__device__ inline void fma8(const u32x4& u, float nw, float* a) {
#pragma unroll
    for (int q = 0; q < 4; ++q) {
        a[2 * q]     = fmaf(nw, __uint_as_float(u[q] << 16), a[2 * q]);
        a[2 * q + 1] = fmaf(nw, __uint_as_float(u[q] & 0xffff0000u), a[2 * q + 1]);
    }
}

// Fused aggregate + GEMM: per block of 256 threads, aggregate 64 node rows
// (4x16-lane gather groups per wave, 16 nodes per wave) into a bf16 LDS tile,
// then Hout = relu((A_agg @ W) + b) via 16x16x32 MFMA with A from LDS.
// LDS row stride 68 u32 (272B): 4-bank rotation per row -> balanced b128 reads.
__global__ __launch_bounds__(256) void k_aggemm(const unsigned int* __restrict__ Hin,
        const int2* __restrict__ csr, const int* __restrict__ rowptr,
        const float* __restrict__ dinv, const unsigned short* __restrict__ Wt,
        const float* __restrict__ bias, unsigned short* __restrict__ Hout, int N) {
    __shared__ unsigned int lds[64][68];
    int wv = threadIdx.x >> 6;
    int lane = threadIdx.x & 63;
    int g = lane >> 4;        // gather group 0..3
    int l16 = lane & 15;      // 16B chunk within row
    int n0 = blockIdx.x * 64;

    // ---- gather phase: wave wv aggregates rows wv*16 .. wv*16+15 ----
    for (int t = 0; t < 16; ++t) {
        int r = wv * 16 + t;
        int w = n0 + r;
        float a[8];
#pragma unroll
        for (int e = 0; e < 8; ++e) a[e] = 0.f;
        if (w < N) {
            int beg = rowptr[w], end = rowptr[w + 1];
            int trips = (end - beg + 3) >> 2;
            int j = beg + g;
#pragma unroll 2
            for (int tt = 0; tt < trips; ++tt, j += 4) {
                int s = w;
                float nw = 0.f;
                if (j < end) { int2 e2 = csr[j]; s = e2.x; nw = __int_as_float(e2.y); }
                u32x4 u = reinterpret_cast<const u32x4*>(Hin + (size_t)s * (NHID / 2))[l16];
                fma8(u, nw, a);
            }
            if (g == 0) {
                float di = dinv[w];
                u32x4 u = reinterpret_cast<const u32x4*>(Hin + (size_t)w * (NHID / 2))[l16];
                fma8(u, di * di, a);
            }
        }
#pragma unroll
        for (int e = 0; e < 8; ++e) {
            a[e] += __shfl_xor(a[e], 16);
            a[e] += __shfl_xor(a[e], 32);
        }
        if (g == 0) {
            u32x4 o;
            o[0] = packbf(a[0], a[1]);
            o[1] = packbf(a[2], a[3]);
            o[2] = packbf(a[4], a[5]);
            o[3] = packbf(a[6], a[7]);
            *reinterpret_cast<u32x4*>(&lds[r][l16 * 4]) = o;
        }
    }
    __syncthreads();

    // ---- MFMA phase: wave wv computes rows wv*16..+15 x 128 cols ----
    int lr = lane & 15;
    int kq = lane >> 4;
    f32x4 acc[8];
#pragma unroll
    for (int nt = 0; nt < 8; ++nt) acc[nt] = 0.f;
#pragma unroll
    for (int kg = 0; kg < 4; ++kg) {
        int kb = kg * 32 + kq * 8;
        bf16x8 af = *reinterpret_cast<const bf16x8*>(&lds[wv * 16 + lr][kb >> 1]);
#pragma unroll
        for (int nt = 0; nt < 8; ++nt) {
            bf16x8 bf = *reinterpret_cast<const bf16x8*>(Wt + (size_t)(nt * 16 + lr) * NHID + kb);
            acc[nt] = __builtin_amdgcn_mfma_f32_16x16x32_bf16(af, bf, acc[nt], 0, 0, 0);
        }
    }
    int r0 = n0 + wv * 16;
#pragma unroll
    for (int nt = 0; nt < 8; ++nt) {
        int c = nt * 16 + lr;
        float b = bias[c];
#pragma unroll
        for (int e = 0; e < 4; ++e) {
            int r = r0 + kq * 4 + e;
            if (r < N) {
                float v = fmaxf(acc[nt][e] + b, 0.f);
                Hout[(size_t)r * NHID + c] = f2bf(v);
            }
        }
    }
}

// BN (eval) + segment-max over sorted batch via encoded atomicMax; bf16 input
__global__ __launch_bounds__(256) void k_bnmax(const unsigned short* __restrict__ Hb,
        const int* __restrict__ batch, const float* __restrict__ gamma,
        const float* __restrict__ beta, const float* __restrict__ rmean,
        const float* __restrict__ rvar, unsigned int* __restrict__ keys, int N) {
    int c = threadIdx.x & 127;
    int h = threadIdx.x >> 7;     // 0..1
    int n0 = blockIdx.x * 64;
    float sc = gamma[c] * rsqrtf(rvar[c] + 1e-5f);
    float sh = beta[c] - rmean[c] * sc;
    int cur = -1;
    float m = -3.0e38f;
    int nend = n0 + 64 < N ? n0 + 64 : N;
    for (int n = n0 + h; n < nend; n += 2) {
        int g = batch[n];
        if (g != cur) {
            if (cur >= 0) atomicMax(&keys[(size_t)cur * NHID + c], fenc(m));
            cur = g;
            m = -3.0e38f;
        }
        float hv = __uint_as_float(((unsigned)Hb[(size_t)n * NHID + c]) << 16);
        float y = fmaf(hv, sc, sh);
        m = fmaxf(m, y);
    }
    if (cur >= 0) atomicMax(&keys[(size_t)cur * NHID + c], fenc(m));
}

// fused head: decode keys -> relu(G@lw1+lb1) -> relu(@lw2+lb2) -> @lw3+lb3
// one block (128 threads) per graph row
__global__ __launch_bounds__(128) void k_head(const unsigned int* __restrict__ keys,
        const float* __restrict__ lw1, const float* __restrict__ lb1,
        const float* __restrict__ lw2, const float* __restrict__ lb2,
        const float* __restrict__ lw3, const float* __restrict__ lb3,
        float* __restrict__ out) {
    __shared__ float g0[NHID], g1[NHID], g2[64];
    int r = blockIdx.x;
    int t = threadIdx.x;
    unsigned int u = keys[(size_t)r * NHID + t];
    g0[t] = (u == 0u) ? -3.0e38f : fdec(u);
    __syncthreads();
    float acc = lb1[t];
#pragma unroll 8
    for (int k = 0; k < NHID; ++k) acc = fmaf(g0[k], lw1[k * NHID + t], acc);
    g1[t] = fmaxf(acc, 0.f);
    __syncthreads();
    if (t < 64) {
        acc = lb2[t];
#pragma unroll 8
        for (int k = 0; k < NHID; ++k) acc = fmaf(g1[k], lw2[k * 64 + t], acc);
        g2[t] = fmaxf(acc, 0.f);
    }
    __syncthreads();
    if (t < NCLS) {
        acc = lb3[t];
#pragma unroll 8
        for (int k = 0; k < 64; ++k) acc = fmaf(g2[k], lw3[k * NCLS + t], acc);
        out[(size_t)r * NCLS + t] = acc;
    }
}

extern "C" void kernel_launch(void* const* d_in, const int* in_sizes, int n_in,
                              void* d_out, int out_size, void* d_ws, size_t ws_size,
                              hipStream_t stream) {
    const float* x     = (const float*)d_in[0];
    const int*   ei    = (const int*)d_in[1];
    const int*   batch = (const int*)d_in[2];
    const float* W1 = (const float*)d_in[3];
    const float* b1 = (const float*)d_in[4];
    const float* W2 = (const float*)d_in[5];
    const float* b2 = (const float*)d_in[6];
    const float* W3 = (const float*)d_in[7];
    const float* b3 = (const float*)d_in[8];
    const float* gamma = (const float*)d_in[9];
    const float* beta  = (const float*)d_in[10];
    const float* rmean = (const float*)d_in[11];
    const float* rvar  = (const float*)d_in[12];
    const float* lw1 = (const float*)d_in[13];
    const float* lb1 = (const float*)d_in[14];
    const float* lw2 = (const float*)d_in[15];
    const float* lb2 = (const float*)d_in[16];
    const float* lw3 = (const float*)d_in[17];
    const float* lb3 = (const float*)d_in[18];

    const int N = in_sizes[2];
    const int E = in_sizes[1] / 2;
    const int* src = ei;
    const int* dst = ei + E;

    char* ws = (char*)d_ws;
    size_t off = 0;
    auto alloc = [&](size_t bytes) {
        char* p = ws + off;
        off += (bytes + 255) & ~(size_t)255;
        return p;
    };
    int*   cnt     = (int*)  alloc((size_t)N * 8);     // cnt[N] + cursor[N], one memset
    int*   cursor  = cnt + N;
    int*   rowptr  = (int*)  alloc(((size_t)N + 1) * 4);
    int*   bsum    = (int*)  alloc(1024 * 4);
    float* dinv    = (float*)alloc((size_t)N * 4);
    int2*  csr     = (int2*) alloc((size_t)E * 8);
    unsigned int* xb = (unsigned int*)alloc((size_t)N * NHID * 2);
    unsigned int* Hb = (unsigned int*)alloc((size_t)N * NHID * 2);
    unsigned short* Wt = (unsigned short*)alloc((size_t)3 * NHID * NHID * 2);
    unsigned int* keys = (unsigned int*)alloc((size_t)NGRAPH * NHID * 4);
    (void)ws_size; (void)n_in; (void)out_size;

    hipMemsetAsync(cnt, 0, (size_t)N * 8, stream);
    hipMemsetAsync(keys, 0, (size_t)NGRAPH * NHID * 4, stream);

    int eb = (E + 255) / 256;
    int nb1 = (N + 1023) / 1024;
    k_deg<<<eb, 256, 0, stream>>>(dst, cnt, E);
    k_scan1<<<nb1, 1024, 0, stream>>>(cnt, dinv, rowptr, bsum, N);
    k_scan2<<<1, 1024, 0, stream>>>(bsum, nb1);
    k_scan3<<<(N + 255) / 256, 256, 0, stream>>>(rowptr, bsum, N);
    k_fill<<<eb, 256, 0, stream>>>(src, dst, dinv, rowptr, cursor, csr, E);
    k_wt3<<<192, 256, 0, stream>>>(W1, W2, W3, Wt);
    k_xbf<<<(N * 16 + 255) / 256, 256, 0, stream>>>(x, xb, N * 16);

    int gb = (N + 63) / 64;
    k_aggemm<<<gb, 256, 0, stream>>>(xb, csr, rowptr, dinv, Wt,          b1, (unsigned short*)Hb, N);
    k_aggemm<<<gb, 256, 0, stream>>>(Hb, csr, rowptr, dinv, Wt + 16384, b2, (unsigned short*)Hb, N);
    k_aggemm<<<gb, 256, 0, stream>>>(Hb, csr, rowptr, dinv, Wt + 32768, b3, (unsigned short*)Hb, N);

    k_bnmax<<<gb, 256, 0, stream>>>((const unsigned short*)Hb, batch, gamma, beta, rmean, rvar, keys, N);
    k_head<<<NGRAPH, 128, 0, stream>>>(keys, lw1, lb1, lw2, lb2, lw3, lb3, (float*)d_out);
}

// Round 5
// 280.494 us; speedup vs baseline: 1.1383x; 1.1383x over previous
//
#include <hip/hip_runtime.h>
#include <hip/hip_bf16.h>

#define NHID 128
#define NGRAPH 512
#define NCLS 10

typedef __attribute__((ext_vector_type(8))) short bf16x8;
typedef __attribute__((ext_vector_type(4))) float f32x4;
typedef __attribute__((ext_vector_type(4))) unsigned int u32x4;

// order-preserving float<->uint encoding for atomicMax-based segment max
__device__ inline unsigned int fenc(float f) {
    unsigned int u = __float_as_uint(f);
    return (u & 0x80000000u) ? ~u : (u | 0x80000000u);
}
__device__ inline float fdec(unsigned int u) {
    u = (u & 0x80000000u) ? (u & 0x7fffffffu) : ~u;
    return __uint_as_float(u);
}
// f32 -> bf16 round-to-nearest-even (finite inputs)
__device__ inline unsigned short f2bf(float f) {
    unsigned int u = __float_as_uint(f);
    return (unsigned short)((u + 0x7fffu + ((u >> 16) & 1u)) >> 16);
}
__device__ inline unsigned int packbf(float lo, float hi) {
    return (unsigned)f2bf(lo) | ((unsigned)f2bf(hi) << 16);
}

__global__ void k_deg(const int* __restrict__ dst, int* __restrict__ cnt, int E) {
    int e = blockIdx.x * blockDim.x + threadIdx.x;
    if (e < E) atomicAdd(&cnt[dst[e]], 1);
}

// phase 1: per-block (1024-wide) inclusive scan of cnt into rowptr[i+1],
// block totals into bsum, and dinv as a free rider.
__global__ __launch_bounds__(1024) void k_scan1(const int* __restrict__ cnt,
        float* __restrict__ dinv, int* __restrict__ rowptr,
        int* __restrict__ bsum, int N) {
    __shared__ int lds[1024];
    int t = threadIdx.x;
    int i = blockIdx.x * 1024 + t;
    int v = (i < N) ? cnt[i] : 0;
    if (i < N) dinv[i] = rsqrtf((float)v + 1.0f);
    lds[t] = v;
    __syncthreads();
    for (int off = 1; off < 1024; off <<= 1) {
        int x = (t >= off) ? lds[t - off] : 0;
        __syncthreads();
        lds[t] += x;
        __syncthreads();
    }
    if (i < N) rowptr[i + 1] = lds[t];
    if (t == 1023) bsum[blockIdx.x] = lds[1023];
}

// phase 2: exclusive scan of nb block sums (nb <= 1024), in place
__global__ __launch_bounds__(1024) void k_scan2(int* __restrict__ bsum, int nb) {
    __shared__ int lds[1024];
    int t = threadIdx.x;
    int v = (t < nb) ? bsum[t] : 0;
    lds[t] = v;
    __syncthreads();
    for (int off = 1; off < 1024; off <<= 1) {
        int x = (t >= off) ? lds[t - off] : 0;
        __syncthreads();
        lds[t] += x;
        __syncthreads();
    }
    if (t < nb) bsum[t] = lds[t] - v;
}

// phase 3: add block offsets; rowptr[0]=0
__global__ void k_scan3(int* __restrict__ rowptr, const int* __restrict__ bsum, int N) {
    int i = blockIdx.x * 256 + threadIdx.x;
    if (i < N) rowptr[i + 1] += bsum[i >> 10];
    if (i == 0) rowptr[0] = 0;
}

// build packed CSR entries: (src, norm) in one 8B element
__global__ void k_fill(const int* __restrict__ src, const int* __restrict__ dst,
                       const float* __restrict__ dinv, const int* __restrict__ rowptr,
                       int* __restrict__ cursor, int2* __restrict__ csr, int E) {
    int e = blockIdx.x * blockDim.x + threadIdx.x;
    if (e >= E) return;
    int s = src[e], d = dst[e];
    int pos = rowptr[d] + atomicAdd(&cursor[d], 1);
    csr[pos] = make_int2(s, __float_as_int(dinv[s] * dinv[d]));
}

// prep: x f32 [N,128] -> bf16, and transpose 3x W [128x128] f32 -> Wt bf16 [c][k]
__global__ void k_prep(const float* __restrict__ x, unsigned int* __restrict__ xb, int n8,
                       const float* __restrict__ W1, const float* __restrict__ W2,
                       const float* __restrict__ W3, unsigned short* __restrict__ Wt) {
    int i = blockIdx.x * 256 + threadIdx.x;
    if (i < n8) {
        const float* p = x + (size_t)i * 8;
        f32x4 a = *reinterpret_cast<const f32x4*>(p);
        f32x4 b = *reinterpret_cast<const f32x4*>(p + 4);
        u32x4 o;
        o[0] = packbf(a[0], a[1]);
        o[1] = packbf(a[2], a[3]);
        o[2] = packbf(b[0], b[1]);
        o[3] = packbf(b[2], b[3]);
        *reinterpret_cast<u32x4*>(xb + (size_t)i * 4) = o;
    } else {
        int idx = i - n8;
        if (idx < 3 * 16384) {
            int l = idx >> 14;
            int r = idx & 16383;
            const float* W = (l == 0) ? W1 : (l == 1) ? W2 : W3;
            int c = r & 127, k = r >> 7;
            Wt[l * 16384 + c * NHID + k] = f2bf(W[k * NHID + c]);
        }
    }
}

__device__ inline void fma8(const u32x4& u, float nw, float* a) {
#pragma unroll
    for (int q = 0; q < 4; ++q) {
        a[2 * q]     = fmaf(nw, __uint_as_float(u[q] << 16), a[2 * q]);
        a[2 * q + 1] = fmaf(nw, __uint_as_float(u[q] & 0xffff0000u), a[2 * q + 1]);
    }
}

// one wave per node, 4 x 16-lane gather groups, bf16 input rows (256B each).
// group g handles edges beg+g, beg+g+4, ...; lane (l16) covers cols l16*8..+8.
// cross-group combine via shfl_xor(16),(32); group 0 adds self-loop and writes
// the aggregated row as bf16 (the GEMM consumes bf16 anyway - same rounding pt).
__global__ __launch_bounds__(256) void k_agg(const unsigned int* __restrict__ Hb,
        const int2* __restrict__ csr, const int* __restrict__ rowptr,
        const float* __restrict__ dinv, unsigned int* __restrict__ aggb, int N) {
    int w = (blockIdx.x * 256 + threadIdx.x) >> 6;
    if (w >= N) return;
    int lane = threadIdx.x & 63;
    int g = lane >> 4;        // gather group 0..3
    int l16 = lane & 15;      // 16B chunk within row
    float a[8];
#pragma unroll
    for (int e = 0; e < 8; ++e) a[e] = 0.f;
    int beg = rowptr[w], end = rowptr[w + 1];
    int trips = (end - beg + 3) >> 2;
    int j = beg + g;
#pragma unroll 2
    for (int t = 0; t < trips; ++t, j += 4) {
        int s = w;
        float nw = 0.f;
        if (j < end) { int2 e2 = csr[j]; s = e2.x; nw = __int_as_float(e2.y); }
        u32x4 u = reinterpret_cast<const u32x4*>(Hb + (size_t)s * (NHID / 2))[l16];
        fma8(u, nw, a);
    }
    // self-loop on group 0
    if (g == 0) {
        float di = dinv[w];
        u32x4 u = reinterpret_cast<const u32x4*>(Hb + (size_t)w * (NHID / 2))[l16];
        fma8(u, di * di, a);
    }
    // combine the 4 groups
#pragma unroll
    for (int e = 0; e < 8; ++e) {
        a[e] += __shfl_xor(a[e], 16);
        a[e] += __shfl_xor(a[e], 32);
    }
    if (g == 0) {
        u32x4 o;
        o[0] = packbf(a[0], a[1]);
        o[1] = packbf(a[2], a[3]);
        o[2] = packbf(a[4], a[5]);
        o[3] = packbf(a[6], a[7]);
        *reinterpret_cast<u32x4*>(aggb + (size_t)w * (NHID / 2) + l16 * 4) = o;
    }
}

// Hb_out = relu(A @ W + b) as bf16; A bf16 [M,128] loaded directly as fragments
__global__ __launch_bounds__(256) void k_gemm(const unsigned short* __restrict__ A,
        const unsigned short* __restrict__ Wt, const float* __restrict__ bias,
        unsigned short* __restrict__ Hb, int M) {
    int wave = threadIdx.x >> 6;
    int lane = threadIdx.x & 63;
    int lr = lane & 15;           // A-row / B-col / D-col within tile
    int kq = lane >> 4;           // k subgroup
    int r0 = blockIdx.x * 64 + wave * 16;
    f32x4 acc[8];
#pragma unroll
    for (int nt = 0; nt < 8; ++nt) acc[nt] = 0.f;
    int ar = r0 + lr;
    bool arok = ar < M;
#pragma unroll
    for (int kg = 0; kg < 4; ++kg) {
        int kb = kg * 32 + kq * 8;
        bf16x8 af = bf16x8(0);
        if (arok) af = *reinterpret_cast<const bf16x8*>(A + (size_t)ar * NHID + kb);
#pragma unroll
        for (int nt = 0; nt < 8; ++nt) {
            bf16x8 bf = *reinterpret_cast<const bf16x8*>(Wt + (size_t)(nt * 16 + lr) * NHID + kb);
            acc[nt] = __builtin_amdgcn_mfma_f32_16x16x32_bf16(af, bf, acc[nt], 0, 0, 0);
        }
    }
#pragma unroll
    for (int nt = 0; nt < 8; ++nt) {
        int c = nt * 16 + lr;
        float b = bias[c];
#pragma unroll
        for (int e = 0; e < 4; ++e) {
            int r = r0 + kq * 4 + e;
            if (r < M) {
                float v = fmaxf(acc[nt][e] + b, 0.f);
                Hb[(size_t)r * NHID + c] = f2bf(v);
            }
        }
    }
}

// BN (eval) + segment-max over sorted batch via encoded atomicMax; bf16 input
__global__ __launch_bounds__(256) void k_bnmax(const unsigned short* __restrict__ Hb,
        const int* __restrict__ batch, const float* __restrict__ gamma,
        const float* __restrict__ beta, const float* __restrict__ rmean,
        const float* __restrict__ rvar, unsigned int* __restrict__ keys, int N) {
    int c = threadIdx.x & 127;
    int h = threadIdx.x >> 7;     // 0..1
    int n0 = blockIdx.x * 64;
    float sc = gamma[c] * rsqrtf(rvar[c] + 1e-5f);
    float sh = beta[c] - rmean[c] * sc;
    int cur = -1;
    float m = -3.0e38f;
    int nend = n0 + 64 < N ? n0 + 64 : N;
    for (int n = n0 + h; n < nend; n += 2) {
        int g = batch[n];
        if (g != cur) {
            if (cur >= 0) atomicMax(&keys[(size_t)cur * NHID + c], fenc(m));
            cur = g;
            m = -3.0e38f;
        }
        float hv = __uint_as_float(((unsigned)Hb[(size_t)n * NHID + c]) << 16);
        float y = fmaf(hv, sc, sh);
        m = fmaxf(m, y);
    }
    if (cur >= 0) atomicMax(&keys[(size_t)cur * NHID + c], fenc(m));
}

// fused head: decode keys -> relu(G@lw1+lb1) -> relu(@lw2+lb2) -> @lw3+lb3
// one block (128 threads) per graph row
__global__ __launch_bounds__(128) void k_head(const unsigned int* __restrict__ keys,
        const float* __restrict__ lw1, const float* __restrict__ lb1,
        const float* __restrict__ lw2, const float* __restrict__ lb2,
        const float* __restrict__ lw3, const float* __restrict__ lb3,
        float* __restrict__ out) {
    __shared__ float g0[NHID], g1[NHID], g2[64];
    int r = blockIdx.x;
    int t = threadIdx.x;
    unsigned int u = keys[(size_t)r * NHID + t];
    g0[t] = (u == 0u) ? -3.0e38f : fdec(u);
    __syncthreads();
    float acc = lb1[t];
#pragma unroll 8
    for (int k = 0; k < NHID; ++k) acc = fmaf(g0[k], lw1[k * NHID + t], acc);
    g1[t] = fmaxf(acc, 0.f);
    __syncthreads();
    if (t < 64) {
        acc = lb2[t];
#pragma unroll 8
        for (int k = 0; k < NHID; ++k) acc = fmaf(g1[k], lw2[k * 64 + t], acc);
        g2[t] = fmaxf(acc, 0.f);
    }
    __syncthreads();
    if (t < NCLS) {
        acc = lb3[t];
#pragma unroll 8
        for (int k = 0; k < 64; ++k) acc = fmaf(g2[k], lw3[k * NCLS + t], acc);
        out[(size_t)r * NCLS + t] = acc;
    }
}

extern "C" void kernel_launch(void* const* d_in, const int* in_sizes, int n_in,
                              void* d_out, int out_size, void* d_ws, size_t ws_size,
                              hipStream_t stream) {
    const float* x     = (const float*)d_in[0];
    const int*   ei    = (const int*)d_in[1];
    const int*   batch = (const int*)d_in[2];
    const float* W1 = (const float*)d_in[3];
    const float* b1 = (const float*)d_in[4];
    const float* W2 = (const float*)d_in[5];
    const float* b2 = (const float*)d_in[6];
    const float* W3 = (const float*)d_in[7];
    const float* b3 = (const float*)d_in[8];
    const float* gamma = (const float*)d_in[9];
    const float* beta  = (const float*)d_in[10];
    const float* rmean = (const float*)d_in[11];
    const float* rvar  = (const float*)d_in[12];
    const float* lw1 = (const float*)d_in[13];
    const float* lb1 = (const float*)d_in[14];
    const float* lw2 = (const float*)d_in[15];
    const float* lb2 = (const float*)d_in[16];
    const float* lw3 = (const float*)d_in[17];
    const float* lb3 = (const float*)d_in[18];

    const int N = in_sizes[2];
    const int E = in_sizes[1] / 2;
    const int* src = ei;
    const int* dst = ei + E;

    char* ws = (char*)d_ws;
    size_t off = 0;
    auto alloc = [&](size_t bytes) {
        char* p = ws + off;
        off += (bytes + 255) & ~(size_t)255;
        return p;
    };
    int*   cnt     = (int*)  alloc((size_t)N * 8);     // cnt[N] + cursor[N], one memset
    int*   cursor  = cnt + N;
    int*   rowptr  = (int*)  alloc(((size_t)N + 1) * 4);
    int*   bsum    = (int*)  alloc(1024 * 4);
    float* dinv    = (float*)alloc((size_t)N * 4);
    int2*  csr     = (int2*) alloc((size_t)E * 8);
    unsigned int* xb   = (unsigned int*)alloc((size_t)N * NHID * 2);
    unsigned int* aggb = (unsigned int*)alloc((size_t)N * NHID * 2);
    unsigned int* Hb   = (unsigned int*)alloc((size_t)N * NHID * 2);
    unsigned short* Wt = (unsigned short*)alloc((size_t)3 * NHID * NHID * 2);
    unsigned int* keys = (unsigned int*)alloc((size_t)NGRAPH * NHID * 4);
    (void)ws_size; (void)n_in; (void)out_size;

    hipMemsetAsync(cnt, 0, (size_t)N * 8, stream);
    hipMemsetAsync(keys, 0, (size_t)NGRAPH * NHID * 4, stream);

    int eb = (E + 255) / 256;
    int nb1 = (N + 1023) / 1024;
    k_deg<<<eb, 256, 0, stream>>>(dst, cnt, E);
    k_scan1<<<nb1, 1024, 0, stream>>>(cnt, dinv, rowptr, bsum, N);
    k_scan2<<<1, 1024, 0, stream>>>(bsum, nb1);
    k_scan3<<<(N + 255) / 256, 256, 0, stream>>>(rowptr, bsum, N);
    k_fill<<<eb, 256, 0, stream>>>(src, dst, dinv, rowptr, cursor, csr, E);
    int n8 = N * 16;
    k_prep<<<(n8 + 3 * 16384 + 255) / 256, 256, 0, stream>>>(x, xb, n8, W1, W2, W3, Wt);

    int ab = ((size_t)N * 64 + 255) / 256;   // one wave per node
    int gb = (N + 63) / 64;
    k_agg<<<ab, 256, 0, stream>>>(xb, csr, rowptr, dinv, aggb, N);
    k_gemm<<<gb, 256, 0, stream>>>((const unsigned short*)aggb, Wt, b1, (unsigned short*)Hb, N);
    k_agg<<<ab, 256, 0, stream>>>(Hb, csr, rowptr, dinv, aggb, N);
    k_gemm<<<gb, 256, 0, stream>>>((const unsigned short*)aggb, Wt + 16384, b2, (unsigned short*)Hb, N);
    k_agg<<<ab, 256, 0, stream>>>(Hb, csr, rowptr, dinv, aggb, N);
    k_gemm<<<gb, 256, 0, stream>>>((const unsigned short*)aggb, Wt + 32768, b3, (unsigned short*)Hb, N);

    k_bnmax<<<gb, 256, 0, stream>>>((const unsigned short*)Hb, batch, gamma, beta, rmean, rvar, keys, N);
    k_head<<<NGRAPH, 128, 0, stream>>>(keys, lw1, lb1, lw2, lb2, lw3, lb3, (float*)d_out);
}

// Round 6
// 249.324 us; speedup vs baseline: 1.2807x; 1.1250x over previous
//
#include <hip/hip_runtime.h>
#include <hip/hip_bf16.h>

#define NHID 128
#define NGRAPH 512
#define NCLS 10

typedef __attribute__((ext_vector_type(8))) short bf16x8;
typedef __attribute__((ext_vector_type(4))) float f32x4;
typedef __attribute__((ext_vector_type(4))) unsigned int u32x4;

// order-preserving float<->uint encoding for atomicMax-based segment max
__device__ inline unsigned int fenc(float f) {
    unsigned int u = __float_as_uint(f);
    return (u & 0x80000000u) ? ~u : (u | 0x80000000u);
}
__device__ inline float fdec(unsigned int u) {
    u = (u & 0x80000000u) ? (u & 0x7fffffffu) : ~u;
    return __uint_as_float(u);
}
// f32 -> bf16 round-to-nearest-even (finite inputs)
__device__ inline unsigned short f2bf(float f) {
    unsigned int u = __float_as_uint(f);
    return (unsigned short)((u + 0x7fffu + ((u >> 16) & 1u)) >> 16);
}
__device__ inline unsigned int packbf(float lo, float hi) {
    return (unsigned)f2bf(lo) | ((unsigned)f2bf(hi) << 16);
}

__global__ void k_deg(const int* __restrict__ dst, int* __restrict__ cnt, int E) {
    int e = blockIdx.x * blockDim.x + threadIdx.x;
    if (e < E) atomicAdd(&cnt[dst[e]], 1);
}

// phase 1: per-block (1024-wide) inclusive scan of cnt into rowptr[i+1],
// block totals into bsum, and dinv as a free rider.
__global__ __launch_bounds__(1024) void k_scan1(const int* __restrict__ cnt,
        float* __restrict__ dinv, int* __restrict__ rowptr,
        int* __restrict__ bsum, int N) {
    __shared__ int lds[1024];
    int t = threadIdx.x;
    int i = blockIdx.x * 1024 + t;
    int v = (i < N) ? cnt[i] : 0;
    if (i < N) dinv[i] = rsqrtf((float)v + 1.0f);
    lds[t] = v;
    __syncthreads();
    for (int off = 1; off < 1024; off <<= 1) {
        int x = (t >= off) ? lds[t - off] : 0;
        __syncthreads();
        lds[t] += x;
        __syncthreads();
    }
    if (i < N) rowptr[i + 1] = lds[t];
    if (t == 1023) bsum[blockIdx.x] = lds[1023];
}

// phase 2: exclusive scan of nb block sums (nb <= 1024), in place
__global__ __launch_bounds__(1024) void k_scan2(int* __restrict__ bsum, int nb) {
    __shared__ int lds[1024];
    int t = threadIdx.x;
    int v = (t < nb) ? bsum[t] : 0;
    lds[t] = v;
    __syncthreads();
    for (int off = 1; off < 1024; off <<= 1) {
        int x = (t >= off) ? lds[t - off] : 0;
        __syncthreads();
        lds[t] += x;
        __syncthreads();
    }
    if (t < nb) bsum[t] = lds[t] - v;
}

// phase 3: add block offsets; rowptr[0]=0
__global__ void k_scan3(int* __restrict__ rowptr, const int* __restrict__ bsum, int N) {
    int i = blockIdx.x * 256 + threadIdx.x;
    if (i < N) rowptr[i + 1] += bsum[i >> 10];
    if (i == 0) rowptr[0] = 0;
}

// build packed CSR entries: (src, norm) in one 8B element
__global__ void k_fill(const int* __restrict__ src, const int* __restrict__ dst,
                       const float* __restrict__ dinv, const int* __restrict__ rowptr,
                       int* __restrict__ cursor, int2* __restrict__ csr, int E) {
    int e = blockIdx.x * blockDim.x + threadIdx.x;
    if (e >= E) return;
    int s = src[e], d = dst[e];
    int pos = rowptr[d] + atomicAdd(&cursor[d], 1);
    csr[pos] = make_int2(s, __float_as_int(dinv[s] * dinv[d]));
}

// prep: x f32 [N,128] -> bf16, and transpose 3x W [128x128] f32 -> Wt bf16 [c][k]
__global__ void k_prep(const float* __restrict__ x, unsigned int* __restrict__ xb, int n8,
                       const float* __restrict__ W1, const float* __restrict__ W2,
                       const float* __restrict__ W3, unsigned short* __restrict__ Wt) {
    int i = blockIdx.x * 256 + threadIdx.x;
    if (i < n8) {
        const float* p = x + (size_t)i * 8;
        f32x4 a = *reinterpret_cast<const f32x4*>(p);
        f32x4 b = *reinterpret_cast<const f32x4*>(p + 4);
        u32x4 o;
        o[0] = packbf(a[0], a[1]);
        o[1] = packbf(a[2], a[3]);
        o[2] = packbf(b[0], b[1]);
        o[3] = packbf(b[2], b[3]);
        *reinterpret_cast<u32x4*>(xb + (size_t)i * 4) = o;
    } else {
        int idx = i - n8;
        if (idx < 3 * 16384) {
            int l = idx >> 14;
            int r = idx & 16383;
            const float* W = (l == 0) ? W1 : (l == 1) ? W2 : W3;
            int c = r & 127, k = r >> 7;
            Wt[l * 16384 + c * NHID + k] = f2bf(W[k * NHID + c]);
        }
    }
}

__device__ inline void fma8(const u32x4& u, float nw, float* a) {
#pragma unroll
    for (int q = 0; q < 4; ++q) {
        a[2 * q]     = fmaf(nw, __uint_as_float(u[q] << 16), a[2 * q]);
        a[2 * q + 1] = fmaf(nw, __uint_as_float(u[q] & 0xffff0000u), a[2 * q + 1]);
    }
}

// one wave per node, 4 x 16-lane gather groups, bf16 input rows (256B each).
// Per trip, group g handles FOUR edges (j, j+4, j+8, j+12) so a deg<=16 node
// completes in one trip with 16 independent row-gathers in flight per wave.
// Self-loop row load hoisted before the loop (independent). Cross-group
// combine via shfl_xor(16),(32); group 0 writes the bf16 aggregated row.
__global__ __launch_bounds__(256) void k_agg(const unsigned int* __restrict__ Hb,
        const int2* __restrict__ csr, const int* __restrict__ rowptr,
        const float* __restrict__ dinv, unsigned int* __restrict__ aggb, int N) {
    int w = (blockIdx.x * 256 + threadIdx.x) >> 6;
    if (w >= N) return;
    int lane = threadIdx.x & 63;
    int g = lane >> 4;        // gather group 0..3
    int l16 = lane & 15;      // 16B chunk within row
    float di = dinv[w];
    u32x4 us = reinterpret_cast<const u32x4*>(Hb + (size_t)w * (NHID / 2))[l16];
    float a[8];
#pragma unroll
    for (int e = 0; e < 8; ++e) a[e] = 0.f;
    int beg = rowptr[w], end = rowptr[w + 1];
    int trips = (end - beg + 15) >> 4;
    int j = beg + g;
    for (int t = 0; t < trips; ++t, j += 16) {
        int s0 = w, s1 = w, s2 = w, s3 = w;
        float n0 = 0.f, n1 = 0.f, n2 = 0.f, n3 = 0.f;
        if (j < end)      { int2 e2 = csr[j];      s0 = e2.x; n0 = __int_as_float(e2.y); }
        if (j + 4 < end)  { int2 e2 = csr[j + 4];  s1 = e2.x; n1 = __int_as_float(e2.y); }
        if (j + 8 < end)  { int2 e2 = csr[j + 8];  s2 = e2.x; n2 = __int_as_float(e2.y); }
        if (j + 12 < end) { int2 e2 = csr[j + 12]; s3 = e2.x; n3 = __int_as_float(e2.y); }
        u32x4 u0 = reinterpret_cast<const u32x4*>(Hb + (size_t)s0 * (NHID / 2))[l16];
        u32x4 u1 = reinterpret_cast<const u32x4*>(Hb + (size_t)s1 * (NHID / 2))[l16];
        u32x4 u2 = reinterpret_cast<const u32x4*>(Hb + (size_t)s2 * (NHID / 2))[l16];
        u32x4 u3 = reinterpret_cast<const u32x4*>(Hb + (size_t)s3 * (NHID / 2))[l16];
        fma8(u0, n0, a);
        fma8(u1, n1, a);
        fma8(u2, n2, a);
        fma8(u3, n3, a);
    }
    // self-loop on group 0
    if (g == 0) fma8(us, di * di, a);
    // combine the 4 groups
#pragma unroll
    for (int e = 0; e < 8; ++e) {
        a[e] += __shfl_xor(a[e], 16);
        a[e] += __shfl_xor(a[e], 32);
    }
    if (g == 0) {
        u32x4 o;
        o[0] = packbf(a[0], a[1]);
        o[1] = packbf(a[2], a[3]);
        o[2] = packbf(a[4], a[5]);
        o[3] = packbf(a[6], a[7]);
        *reinterpret_cast<u32x4*>(aggb + (size_t)w * (NHID / 2) + l16 * 4) = o;
    }
}

// Hb_out = relu(A @ W + b) as bf16; A bf16 [M,128] loaded directly as fragments
__global__ __launch_bounds__(256) void k_gemm(const unsigned short* __restrict__ A,
        const unsigned short* __restrict__ Wt, const float* __restrict__ bias,
        unsigned short* __restrict__ Hb, int M) {
    int wave = threadIdx.x >> 6;
    int lane = threadIdx.x & 63;
    int lr = lane & 15;           // A-row / B-col / D-col within tile
    int kq = lane >> 4;           // k subgroup
    int r0 = blockIdx.x * 64 + wave * 16;
    f32x4 acc[8];
#pragma unroll
    for (int nt = 0; nt < 8; ++nt) acc[nt] = 0.f;
    int ar = r0 + lr;
    bool arok = ar < M;
#pragma unroll
    for (int kg = 0; kg < 4; ++kg) {
        int kb = kg * 32 + kq * 8;
        bf16x8 af = bf16x8(0);
        if (arok) af = *reinterpret_cast<const bf16x8*>(A + (size_t)ar * NHID + kb);
#pragma unroll
        for (int nt = 0; nt < 8; ++nt) {
            bf16x8 bf = *reinterpret_cast<const bf16x8*>(Wt + (size_t)(nt * 16 + lr) * NHID + kb);
            acc[nt] = __builtin_amdgcn_mfma_f32_16x16x32_bf16(af, bf, acc[nt], 0, 0, 0);
        }
    }
#pragma unroll
    for (int nt = 0; nt < 8; ++nt) {
        int c = nt * 16 + lr;
        float b = bias[c];
#pragma unroll
        for (int e = 0; e < 4; ++e) {
            int r = r0 + kq * 4 + e;
            if (r < M) {
                float v = fmaxf(acc[nt][e] + b, 0.f);
                Hb[(size_t)r * NHID + c] = f2bf(v);
            }
        }
    }
}

// layer-3 GEMM with fused BN (eval) + segment-max epilogue.
// Block covers 64 consecutive (batch-sorted) rows; per-block LDS segment-max
// pre-reduction, then span*128 global atomicMax flushes.
__global__ __launch_bounds__(256) void k_gemm_bn(const unsigned short* __restrict__ A,
        const unsigned short* __restrict__ Wt, const float* __restrict__ bias,
        const int* __restrict__ batch, const float* __restrict__ gamma,
        const float* __restrict__ beta, const float* __restrict__ rmean,
        const float* __restrict__ rvar, unsigned int* __restrict__ keys, int M) {
    __shared__ unsigned int smax[64][NHID];   // 32 KB
    __shared__ int bseg[64];
    int tid = threadIdx.x;
    int n0 = blockIdx.x * 64;
    for (int i = tid; i < 64 * NHID; i += 256) ((unsigned int*)smax)[i] = 0u;
    if (tid < 64) {
        int r = n0 + tid;
        bseg[tid] = batch[r < M ? r : M - 1];
    }
    int wave = tid >> 6;
    int lane = tid & 63;
    int lr = lane & 15;
    int kq = lane >> 4;
    int r0 = n0 + wave * 16;
    f32x4 acc[8];
#pragma unroll
    for (int nt = 0; nt < 8; ++nt) acc[nt] = 0.f;
    int ar = r0 + lr;
    bool arok = ar < M;
#pragma unroll
    for (int kg = 0; kg < 4; ++kg) {
        int kb = kg * 32 + kq * 8;
        bf16x8 af = bf16x8(0);
        if (arok) af = *reinterpret_cast<const bf16x8*>(A + (size_t)ar * NHID + kb);
#pragma unroll
        for (int nt = 0; nt < 8; ++nt) {
            bf16x8 bf = *reinterpret_cast<const bf16x8*>(Wt + (size_t)(nt * 16 + lr) * NHID + kb);
            acc[nt] = __builtin_amdgcn_mfma_f32_16x16x32_bf16(af, bf, acc[nt], 0, 0, 0);
        }
    }
    __syncthreads();   // smax/bseg init complete
    int glo = bseg[0];
#pragma unroll
    for (int nt = 0; nt < 8; ++nt) {
        int c = nt * 16 + lr;
        float b = bias[c];
        float sc = gamma[c] * rsqrtf(rvar[c] + 1e-5f);
        float sh = beta[c] - rmean[c] * sc;
#pragma unroll
        for (int e = 0; e < 4; ++e) {
            int rr = wave * 16 + kq * 4 + e;      // row within block
            if (n0 + rr < M) {
                float v = fmaxf(acc[nt][e] + b, 0.f);
                float y = fmaf(v, sc, sh);
                atomicMax(&smax[bseg[rr] - glo][c], fenc(y));
            }
        }
    }
    __syncthreads();
    int last = M - 1 - n0;
    if (last > 63) last = 63;
    int span = bseg[last] - glo + 1;
    for (int i = tid; i < span * NHID; i += 256) {
        unsigned int v = ((unsigned int*)smax)[i];
        if (v) atomicMax(&keys[(size_t)(glo + (i >> 7)) * NHID + (i & 127)], v);
    }
}

// fused head: decode keys -> relu(G@lw1+lb1) -> relu(@lw2+lb2) -> @lw3+lb3
// one block (128 threads) per graph row
__global__ __launch_bounds__(128) void k_head(const unsigned int* __restrict__ keys,
        const float* __restrict__ lw1, const float* __restrict__ lb1,
        const float* __restrict__ lw2, const float* __restrict__ lb2,
        const float* __restrict__ lw3, const float* __restrict__ lb3,
        float* __restrict__ out) {
    __shared__ float g0[NHID], g1[NHID], g2[64];
    int r = blockIdx.x;
    int t = threadIdx.x;
    unsigned int u = keys[(size_t)r * NHID + t];
    g0[t] = (u == 0u) ? -3.0e38f : fdec(u);
    __syncthreads();
    float acc = lb1[t];
#pragma unroll 8
    for (int k = 0; k < NHID; ++k) acc = fmaf(g0[k], lw1[k * NHID + t], acc);
    g1[t] = fmaxf(acc, 0.f);
    __syncthreads();
    if (t < 64) {
        acc = lb2[t];
#pragma unroll 8
        for (int k = 0; k < NHID; ++k) acc = fmaf(g1[k], lw2[k * 64 + t], acc);
        g2[t] = fmaxf(acc, 0.f);
    }
    __syncthreads();
    if (t < NCLS) {
        acc = lb3[t];
#pragma unroll 8
        for (int k = 0; k < 64; ++k) acc = fmaf(g2[k], lw3[k * NCLS + t], acc);
        out[(size_t)r * NCLS + t] = acc;
    }
}

extern "C" void kernel_launch(void* const* d_in, const int* in_sizes, int n_in,
                              void* d_out, int out_size, void* d_ws, size_t ws_size,
                              hipStream_t stream) {
    const float* x     = (const float*)d_in[0];
    const int*   ei    = (const int*)d_in[1];
    const int*   batch = (const int*)d_in[2];
    const float* W1 = (const float*)d_in[3];
    const float* b1 = (const float*)d_in[4];
    const float* W2 = (const float*)d_in[5];
    const float* b2 = (const float*)d_in[6];
    const float* W3 = (const float*)d_in[7];
    const float* b3 = (const float*)d_in[8];
    const float* gamma = (const float*)d_in[9];
    const float* beta  = (const float*)d_in[10];
    const float* rmean = (const float*)d_in[11];
    const float* rvar  = (const float*)d_in[12];
    const float* lw1 = (const float*)d_in[13];
    const float* lb1 = (const float*)d_in[14];
    const float* lw2 = (const float*)d_in[15];
    const float* lb2 = (const float*)d_in[16];
    const float* lw3 = (const float*)d_in[17];
    const float* lb3 = (const float*)d_in[18];

    const int N = in_sizes[2];
    const int E = in_sizes[1] / 2;
    const int* src = ei;
    const int* dst = ei + E;

    char* ws = (char*)d_ws;
    size_t off = 0;
    auto alloc = [&](size_t bytes) {
        char* p = ws + off;
        off += (bytes + 255) & ~(size_t)255;
        return p;
    };
    int*   cnt     = (int*)  alloc((size_t)N * 8);     // cnt[N] + cursor[N], one memset
    int*   cursor  = cnt + N;
    int*   rowptr  = (int*)  alloc(((size_t)N + 1) * 4);
    int*   bsum    = (int*)  alloc(1024 * 4);
    float* dinv    = (float*)alloc((size_t)N * 4);
    int2*  csr     = (int2*) alloc((size_t)E * 8);
    unsigned int* xb   = (unsigned int*)alloc((size_t)N * NHID * 2);
    unsigned int* aggb = (unsigned int*)alloc((size_t)N * NHID * 2);
    unsigned int* Hb   = (unsigned int*)alloc((size_t)N * NHID * 2);
    unsigned short* Wt = (unsigned short*)alloc((size_t)3 * NHID * NHID * 2);
    unsigned int* keys = (unsigned int*)alloc((size_t)NGRAPH * NHID * 4);
    (void)ws_size; (void)n_in; (void)out_size;

    hipMemsetAsync(cnt, 0, (size_t)N * 8, stream);
    hipMemsetAsync(keys, 0, (size_t)NGRAPH * NHID * 4, stream);

    int eb = (E + 255) / 256;
    int nb1 = (N + 1023) / 1024;
    k_deg<<<eb, 256, 0, stream>>>(dst, cnt, E);
    k_scan1<<<nb1, 1024, 0, stream>>>(cnt, dinv, rowptr, bsum, N);
    k_scan2<<<1, 1024, 0, stream>>>(bsum, nb1);
    k_scan3<<<(N + 255) / 256, 256, 0, stream>>>(rowptr, bsum, N);
    k_fill<<<eb, 256, 0, stream>>>(src, dst, dinv, rowptr, cursor, csr, E);
    int n8 = N * 16;
    k_prep<<<(n8 + 3 * 16384 + 255) / 256, 256, 0, stream>>>(x, xb, n8, W1, W2, W3, Wt);

    int ab = ((size_t)N * 64 + 255) / 256;   // one wave per node
    int gb = (N + 63) / 64;
    k_agg<<<ab, 256, 0, stream>>>(xb, csr, rowptr, dinv, aggb, N);
    k_gemm<<<gb, 256, 0, stream>>>((const unsigned short*)aggb, Wt, b1, (unsigned short*)Hb, N);
    k_agg<<<ab, 256, 0, stream>>>(Hb, csr, rowptr, dinv, aggb, N);
    k_gemm<<<gb, 256, 0, stream>>>((const unsigned short*)aggb, Wt + 16384, b2, (unsigned short*)Hb, N);
    k_agg<<<ab, 256, 0, stream>>>(Hb, csr, rowptr, dinv, aggb, N);
    k_gemm_bn<<<gb, 256, 0, stream>>>((const unsigned short*)aggb, Wt + 32768, b3,
                                      batch, gamma, beta, rmean, rvar, keys, N);

    k_head<<<NGRAPH, 128, 0, stream>>>(keys, lw1, lb1, lw2, lb2, lw3, lb3, (float*)d_out);
}